// Round 3
// baseline (345.041 us; speedup 1.0000x reference)
//
#include <hip/hip_runtime.h>
#include <stdint.h>

#define HDIM 1024
#define NEXP 32
#define IDIM 512
#define TOPK 6
#define NTOK 2048
#define NPAIR (NTOK*TOPK)   // 12288

typedef __attribute__((ext_vector_type(4))) float f32x4;
typedef __attribute__((ext_vector_type(8))) short s16x8;
typedef __attribute__((ext_vector_type(8))) __bf16 bf16x8;

static __device__ __forceinline__ f32x4 mfma16(s16x8 a, s16x8 b, f32x4 c){
  return __builtin_amdgcn_mfma_f32_16x16x32_bf16(
      __builtin_bit_cast(bf16x8, a), __builtin_bit_cast(bf16x8, b), c, 0, 0, 0);
}

// native cast -> compiler emits v_cvt_pk_bf16_f32 (2 elems/inst)
static __device__ __forceinline__ short bf1(float f){
  return __builtin_bit_cast(short, (__bf16)f);
}
static __device__ __forceinline__ s16x8 pack8(float4 a, float4 b){
  bf16x8 o;
  o[0]=(__bf16)a.x; o[1]=(__bf16)a.y; o[2]=(__bf16)a.z; o[3]=(__bf16)a.w;
  o[4]=(__bf16)b.x; o[5]=(__bf16)b.y; o[6]=(__bf16)b.z; o[7]=(__bf16)b.w;
  return __builtin_bit_cast(s16x8, o);
}

// ---- stage a [ROWS x 64] bf16 tile into LDS via global_load_lds -----------
// LDS dest linear (HW requirement); global source column pre-XORed so the
// swizzled reader (frag_ld) sees the logical layout (rule 21).
template<int ROWS, typename RowFn>
static __device__ __forceinline__ void stage_tile(const short* __restrict__ g, int ldg,
                                                  short* lds, int k0, int tid, RowFn rowOf){
  #pragma unroll
  for (int pss = 0; pss < ROWS/32; ++pss){
    int chunk = pss*256 + tid;          // wave-contiguous: base + lane*16B
    int row   = chunk >> 3;             // 8 x 16B chunks per 128B row
    int kb    = (chunk & 7) << 4;       // linear byte col
    int skb   = kb ^ ((row & 7) << 4);  // pre-swizzled source col
    const short* src = g + (long)rowOf(row)*ldg + k0 + (skb >> 1);
    __builtin_amdgcn_global_load_lds((const __attribute__((address_space(1))) void*)src,
                                     (__attribute__((address_space(3))) void*)(lds + chunk*8),
                                     16, 0, 0);
  }
}

// ---- stage a [ROWS x 64] tile from FP32 source, converting to bf16 --------
// reg-staging: 2x float4 -> cvt_pk -> ds_write_b128 at the swizzled offset
// (write-side swizzle matches frag_ld's read-side XOR).
template<int ROWS>
static __device__ __forceinline__ void stage_f32(const float* __restrict__ g, int ldg,
                                                 short* lds, int k0, int tid){
  #pragma unroll
  for (int pss = 0; pss < ROWS/32; ++pss){
    int chunk = pss*256 + tid;          // 16B bf16 chunk = 8 elems
    int row   = chunk >> 3;
    int kc    = (chunk & 7) * 8;        // element col within 64
    const float4* src = (const float4*)(g + (long)row*ldg + k0 + kc);
    float4 v0 = src[0], v1 = src[1];
    int kb  = (chunk & 7) << 4;
    int off = row*128 + (kb ^ ((row & 7) << 4));
    *(s16x8*)(lds + (off >> 1)) = pack8(v0, v1);
  }
}

// fragment read: lane holds 8 consecutive k of row (lane&15), k-chunk (lane>>4)*8
static __device__ __forceinline__ s16x8 frag_ld(const short* lds, int row, int ks, int lane){
  int kb  = ks*64 + ((lane >> 4) << 4);
  int off = row*128 + (kb ^ ((row & 7) << 4));
  return *(const s16x8*)(lds + (off >> 1));
}

__global__ void k_zero(int* __restrict__ counts){
  if (threadIdx.x < NEXP) counts[threadIdx.x] = 0;
}

// ---------------- router: logits, softmax, top-6, counts, x->bf16 ----------
__global__ __launch_bounds__(256) void k_router(const float* __restrict__ x,
    const float* __restrict__ wr, const float* __restrict__ bias,
    short* __restrict__ xb, int* __restrict__ tki, float* __restrict__ tkw,
    int* __restrict__ counts){
  int t = blockIdx.x, tid = threadIdx.x, lane = tid & 63, wid = tid >> 6;
  __shared__ float xs[HDIM];
  __shared__ float lg[NEXP];
  const float4* xr = (const float4*)(x + (long)t*HDIM);
  float4 v = xr[tid];
  ((float4*)xs)[tid] = v;
  short4 o; o.x = bf1(v.x); o.y = bf1(v.y); o.z = bf1(v.z); o.w = bf1(v.w);
  *(short4*)(xb + (long)t*HDIM + tid*4) = o;
  __syncthreads();
  #pragma unroll
  for (int j = 0; j < 8; ++j){
    int e = wid*8 + j;
    const float* w = wr + (long)e*HDIM;
    float acc = 0.f;
    for (int k = lane; k < HDIM; k += 64) acc += xs[k]*w[k];
    for (int s = 32; s; s >>= 1) acc += __shfl_xor(acc, s);
    if (lane == 0) lg[e] = acc;
  }
  __syncthreads();
  if (wid == 0){
    float l = (lane < NEXP) ? lg[lane] : -1e30f;
    float m = l;
    for (int s = 32; s; s >>= 1) m = fmaxf(m, __shfl_xor(m, s));
    float p = (lane < NEXP) ? __expf(l - m) : 0.f;
    float sum = p;
    for (int s = 32; s; s >>= 1) sum += __shfl_xor(sum, s);
    p = p / sum;
    float rem = (lane < NEXP) ? (p + bias[lane]) : -1e30f;
    int myidx = 0; float myw = 0.f;
    for (int k = 0; k < TOPK; ++k){
      float vv = rem; int ix = lane;
      for (int s = 32; s; s >>= 1){
        float ov = __shfl_xor(vv, s); int oi = __shfl_xor(ix, s);
        if (ov > vv || (ov == vv && oi < ix)){ vv = ov; ix = oi; }
      }
      float pw = __shfl(p, ix);
      if (lane == ix) rem = -1e30f;
      if (lane == k){ myidx = ix; myw = pw; }
    }
    float s6 = (lane < TOPK) ? myw : 0.f;
    for (int s = 32; s; s >>= 1) s6 += __shfl_xor(s6, s);
    if (lane < TOPK){
      tki[t*TOPK + lane] = myidx;
      tkw[t*TOPK + lane] = myw / fmaxf(s6, 1e-12f);
      atomicAdd(&counts[myidx], 1);
    }
  }
}

__global__ void k_scan(const int* __restrict__ counts, int* __restrict__ offsets,
                       int* __restrict__ cursor){
  if (threadIdx.x == 0){
    int s = 0;
    for (int e = 0; e < NEXP; ++e){ offsets[e] = s; cursor[e] = s; s += counts[e]; }
    offsets[NEXP] = s;
  }
}

__global__ void k_scatter(const int* __restrict__ tki, const float* __restrict__ tkw,
                          int* __restrict__ cursor, int* __restrict__ permt,
                          float* __restrict__ permw){
  int i = blockIdx.x*256 + threadIdx.x;
  if (i < NPAIR){
    int e = tki[i];
    int pos = atomicAdd(&cursor[e], 1);
    permt[pos] = i / TOPK;
    permw[pos] = tkw[i];
  }
}

// ---------------- merged gate+up (expert z<32, shared z==32) ---------------
// expert: A = gathered xb rows (permt), B = wgu[e] (gate | up), out -> hmid
// shared: A = xb rows m0.., B = wsg/wsu, out -> sb
__global__ __launch_bounds__(256) void k_gu(const short* __restrict__ xb,
    const float* __restrict__ wgu, const float* __restrict__ wsg,
    const float* __restrict__ wsu, const int* __restrict__ offsets,
    const int* __restrict__ permt, short* __restrict__ hmid, short* __restrict__ sb){
  bool expert = (blockIdx.z < NEXP);
  int tid = threadIdx.x, lane = tid & 63, wid = tid >> 6, wr = wid >> 1, wc = wid & 1;
  __shared__ short As[128*64], Bg[64*64], Bu[64*64];
  __shared__ int rowmap[128];
  int m0 = blockIdx.y*128, n0;
  int off = 0, seg = NTOK;
  const float *wg, *wu;
  if (expert){
    if (blockIdx.x >= 8) return;
    int e = blockIdx.z;
    off = offsets[e]; seg = offsets[e+1] - off;
    if (m0 >= seg) return;
    n0 = blockIdx.x*64;
    wg = wgu + (long)e*1024*HDIM + (long)n0*HDIM;
    wu = wg + (long)IDIM*HDIM;
    if (tid < 128) rowmap[tid] = permt[off + min(m0 + tid, seg - 1)];
  } else {
    n0 = blockIdx.x*64;
    wg = wsg + (long)n0*HDIM;
    wu = wsu + (long)n0*HDIM;
    if (tid < 128) rowmap[tid] = m0 + tid;
  }
  f32x4 z = {0.f,0.f,0.f,0.f};
  f32x4 ag[4][2], au[4][2];
  for (int i=0;i<4;i++) for (int j=0;j<2;j++){ ag[i][j]=z; au[i][j]=z; }
  for (int kt = 0; kt < HDIM/64; ++kt){
    __syncthreads();
    int k0 = kt*64;
    stage_tile<128>(xb, HDIM, As, k0, tid, [&](int r){ return rowmap[r]; });
    stage_f32<64>(wg, HDIM, Bg, k0, tid);
    stage_f32<64>(wu, HDIM, Bu, k0, tid);
    __syncthreads();
    #pragma unroll
    for (int ks = 0; ks < 2; ++ks){
      s16x8 af[4], bg[2], bu[2];
      #pragma unroll
      for (int i = 0; i < 4; ++i) af[i] = frag_ld(As, wr*64 + i*16 + (lane&15), ks, lane);
      #pragma unroll
      for (int j = 0; j < 2; ++j){
        bg[j] = frag_ld(Bg, wc*32 + j*16 + (lane&15), ks, lane);
        bu[j] = frag_ld(Bu, wc*32 + j*16 + (lane&15), ks, lane);
      }
      #pragma unroll
      for (int i = 0; i < 4; ++i)
        #pragma unroll
        for (int j = 0; j < 2; ++j){
          ag[i][j] = mfma16(af[i], bg[j], ag[i][j]);
          au[i][j] = mfma16(af[i], bu[j], au[i][j]);
        }
    }
  }
  #pragma unroll
  for (int i = 0; i < 4; ++i){
    int mrow = wr*64 + i*16 + ((lane >> 4) << 2);
    #pragma unroll
    for (int j = 0; j < 2; ++j){
      int col = n0 + wc*32 + j*16 + (lane & 15);
      #pragma unroll
      for (int r = 0; r < 4; ++r){
        int m = mrow + r;
        float gv = ag[i][j][r], uv = au[i][j][r];
        float sv = gv / (1.f + __expf(-gv)) * uv;
        if (expert){
          if (m0 + m < seg)
            hmid[(long)(off + m0 + m)*IDIM + col] = bf1(sv);
        } else {
          sb[(long)(m0 + m)*1024 + col] = bf1(sv);
        }
      }
    }
  }
}

// ---------------- merged down (expert z<32, shared z==32) ------------------
// expert: A = hmid segment rows, B = wdn[e], out += w * acc (atomic)
// shared: A = sb rows, B = wsd, out += acc (atomic; out pre-zeroed)
__global__ __launch_bounds__(256) void k_down(const short* __restrict__ hmid,
    const float* __restrict__ wdn, const short* __restrict__ sb,
    const float* __restrict__ wsd, const int* __restrict__ offsets,
    const int* __restrict__ permt, const float* __restrict__ permw,
    float* __restrict__ out){
  bool expert = (blockIdx.z < NEXP);
  int tid = threadIdx.x, lane = tid & 63, wid = tid >> 6, wr = wid >> 1, wc = wid & 1;
  __shared__ short As[128*64], Bs[128*64];
  __shared__ int rowmap[128];
  int m0 = blockIdx.y*128, n0 = blockIdx.x*128;
  int off = 0, seg = NTOK, nkt, lda, ldb;
  const short* Ag; const float* Bgp;
  if (expert){
    int e = blockIdx.z;
    off = offsets[e]; seg = offsets[e+1] - off;
    if (m0 >= seg) return;
    Ag = hmid; lda = IDIM;
    Bgp = wdn + (long)e*HDIM*IDIM + (long)n0*IDIM; ldb = IDIM;
    nkt = IDIM/64;
    if (tid < 128) rowmap[tid] = off + min(m0 + tid, seg - 1);
  } else {
    Ag = sb; lda = 1024;
    Bgp = wsd + (long)n0*1024; ldb = 1024;
    nkt = 1024/64;
    if (tid < 128) rowmap[tid] = m0 + tid;
  }
  f32x4 z = {0.f,0.f,0.f,0.f};
  f32x4 acc[4][4];
  for (int i=0;i<4;i++) for (int j=0;j<4;j++) acc[i][j]=z;
  for (int kt = 0; kt < nkt; ++kt){
    __syncthreads();
    int k0 = kt*64;
    stage_tile<128>(Ag, lda, As, k0, tid, [&](int r){ return rowmap[r]; });
    stage_f32<128>(Bgp, ldb, Bs, k0, tid);
    __syncthreads();
    #pragma unroll
    for (int ks = 0; ks < 2; ++ks){
      s16x8 af[4], bf[4];
      #pragma unroll
      for (int i = 0; i < 4; ++i){
        af[i] = frag_ld(As, wr*64 + i*16 + (lane&15), ks, lane);
        bf[i] = frag_ld(Bs, wc*64 + i*16 + (lane&15), ks, lane);
      }
      #pragma unroll
      for (int i = 0; i < 4; ++i)
        #pragma unroll
        for (int j = 0; j < 4; ++j)
          acc[i][j] = mfma16(af[i], bf[j], acc[i][j]);
    }
  }
  if (expert){
    #pragma unroll
    for (int i = 0; i < 4; ++i){
      int mrow = wr*64 + i*16 + ((lane >> 4) << 2);
      #pragma unroll
      for (int r = 0; r < 4; ++r){
        int m = mrow + r;
        if (m0 + m < seg){
          int p = off + m0 + m;
          int t = permt[p];
          float w = permw[p];
          #pragma unroll
          for (int j = 0; j < 4; ++j){
            int col = n0 + wc*64 + j*16 + (lane & 15);
            atomicAdd(&out[(long)t*HDIM + col], w*acc[i][j][r]);
          }
        }
      }
    }
  } else {
    #pragma unroll
    for (int i = 0; i < 4; ++i){
      int mrow = m0 + wr*64 + i*16 + ((lane >> 4) << 2);
      #pragma unroll
      for (int j = 0; j < 4; ++j){
        int col = n0 + wc*64 + j*16 + (lane & 15);
        #pragma unroll
        for (int r = 0; r < 4; ++r)
          atomicAdd(&out[(long)(mrow + r)*HDIM + col], acc[i][j][r]);
      }
    }
  }
}

extern "C" void kernel_launch(void* const* d_in, const int* in_sizes, int n_in,
                              void* d_out, int out_size, void* d_ws, size_t ws_size,
                              hipStream_t stream){
  const float* x    = (const float*)d_in[0];
  const float* rw   = (const float*)d_in[1];
  const float* bias = (const float*)d_in[2];
  const float* wgu  = (const float*)d_in[3];
  const float* wdn  = (const float*)d_in[4];
  const float* wsg  = (const float*)d_in[5];
  const float* wsu  = (const float*)d_in[6];
  const float* wsd  = (const float*)d_in[7];
  float* out = (float*)d_out;

  char* ws = (char*)d_ws;
  size_t o = 0;
  auto alloc = [&](size_t bytes){ void* p = ws + o; o += (bytes + 255) & ~(size_t)255; return p; };
  short* xb   = (short*)alloc(4194304);    // [T,H] bf16
  short* sb   = (short*)alloc(4194304);    // [T,IS] bf16
  short* hmid = (short*)alloc(12582912);   // [P,I] bf16
  int*   tki  = (int*)alloc(NPAIR*4);
  float* tkw  = (float*)alloc(NPAIR*4);
  int*   counts  = (int*)alloc(256);
  int*   offsets = (int*)alloc(256);
  int*   cursor  = (int*)alloc(256);
  int*   permt   = (int*)alloc(NPAIR*4);
  float* permw   = (float*)alloc(NPAIR*4);
  (void)ws_size; (void)in_sizes; (void)n_in;

  hipMemsetAsync(out, 0, (size_t)out_size*4, stream);
  k_zero<<<dim3(1), dim3(64), 0, stream>>>(counts);
  k_router<<<dim3(NTOK), dim3(256), 0, stream>>>(x, rw, bias, xb, tki, tkw, counts);
  k_scan<<<dim3(1), dim3(64), 0, stream>>>(counts, offsets, cursor);
  k_scatter<<<dim3((NPAIR+255)/256), dim3(256), 0, stream>>>(tki, tkw, cursor, permt, permw);
  k_gu<<<dim3(16, 16, NEXP+1), dim3(256), 0, stream>>>(xb, wgu, wsg, wsu, offsets, permt, hmid, sb);
  k_down<<<dim3(8, 16, NEXP+1), dim3(256), 0, stream>>>(hmid, wdn, sb, wsd, offsets, permt, permw, out);
}

// Round 4
// 277.385 us; speedup vs baseline: 1.2439x; 1.2439x over previous
//
#include <hip/hip_runtime.h>
#include <stdint.h>

#define HDIM 1024
#define NEXP 32
#define IDIM 512
#define TOPK 6
#define NTOK 2048
#define NPAIR (NTOK*TOPK)   // 12288

typedef __attribute__((ext_vector_type(4))) float f32x4;
typedef __attribute__((ext_vector_type(8))) short s16x8;
typedef __attribute__((ext_vector_type(8))) __bf16 bf16x8;

static __device__ __forceinline__ f32x4 mfma16(s16x8 a, s16x8 b, f32x4 c){
  return __builtin_amdgcn_mfma_f32_16x16x32_bf16(
      __builtin_bit_cast(bf16x8, a), __builtin_bit_cast(bf16x8, b), c, 0, 0, 0);
}

static __device__ __forceinline__ short bf1(float f){
  return __builtin_bit_cast(short, (__bf16)f);
}
static __device__ __forceinline__ s16x8 pack8(float4 a, float4 b){
  bf16x8 o;
  o[0]=(__bf16)a.x; o[1]=(__bf16)a.y; o[2]=(__bf16)a.z; o[3]=(__bf16)a.w;
  o[4]=(__bf16)b.x; o[5]=(__bf16)b.y; o[6]=(__bf16)b.z; o[7]=(__bf16)b.w;
  return __builtin_bit_cast(s16x8, o);
}

// ---- issue async stage of a [ROWS x 64] bf16 tile via global_load_lds -----
// LDS dest linear (HW requirement); global source column pre-XORed so the
// swizzled reader (frag_ld) sees the logical layout (rule 21).
template<int ROWS, typename RowFn>
static __device__ __forceinline__ void issueA(const short* __restrict__ g, int ldg,
                                              short* lds, int k0, int tid, RowFn rowOf){
  #pragma unroll
  for (int pss = 0; pss < ROWS/32; ++pss){
    int chunk = pss*256 + tid;          // 8 x 16B chunks per 128B row
    int row   = chunk >> 3;
    int kb    = (chunk & 7) << 4;
    int skb   = kb ^ ((row & 7) << 4);  // pre-swizzled source col
    const short* src = g + (long)rowOf(row)*ldg + k0 + (skb >> 1);
    __builtin_amdgcn_global_load_lds((const __attribute__((address_space(1))) void*)src,
                                     (__attribute__((address_space(3))) void*)(lds + chunk*8),
                                     16, 0, 0);
  }
}

// ---- fp32 B tile: load to regs (issue-early) / cvt+write-late (T14) -------
template<int ROWS>
static __device__ __forceinline__ void loadB(const float* __restrict__ g, int ldg,
                                             int k0, int tid, float4 (*r)[2]){
  #pragma unroll
  for (int p = 0; p < ROWS/32; ++p){
    int chunk = p*256 + tid, row = chunk >> 3, kc = (chunk & 7)*8;
    const float4* s = (const float4*)(g + (long)row*ldg + k0 + kc);
    r[p][0] = s[0]; r[p][1] = s[1];
  }
}
template<int ROWS>
static __device__ __forceinline__ void writeB(short* lds, int tid, float4 (*r)[2]){
  #pragma unroll
  for (int p = 0; p < ROWS/32; ++p){
    int chunk = p*256 + tid, row = chunk >> 3, kb = (chunk & 7) << 4;
    int off = row*128 + (kb ^ ((row & 7) << 4));
    *(s16x8*)(lds + (off >> 1)) = pack8(r[p][0], r[p][1]);
  }
}

// fragment read: lane holds 8 consecutive k of row, k-chunk (lane>>4)*8
static __device__ __forceinline__ s16x8 frag_ld(const short* lds, int row, int ks, int lane){
  int kb  = ks*64 + ((lane >> 4) << 4);
  int off = row*128 + (kb ^ ((row & 7) << 4));
  return *(const s16x8*)(lds + (off >> 1));
}

__global__ void k_zero(int* __restrict__ counts){
  if (threadIdx.x < NEXP) counts[threadIdx.x] = 0;
}

// ---------------- router: logits, softmax, top-6, counts, x->bf16 ----------
__global__ __launch_bounds__(256) void k_router(const float* __restrict__ x,
    const float* __restrict__ wr, const float* __restrict__ bias,
    short* __restrict__ xb, int* __restrict__ tki, float* __restrict__ tkw,
    int* __restrict__ counts){
  int t = blockIdx.x, tid = threadIdx.x, lane = tid & 63, wid = tid >> 6;
  __shared__ float xs[HDIM];
  __shared__ float lg[NEXP];
  const float4* xr = (const float4*)(x + (long)t*HDIM);
  float4 v = xr[tid];
  ((float4*)xs)[tid] = v;
  short4 o; o.x = bf1(v.x); o.y = bf1(v.y); o.z = bf1(v.z); o.w = bf1(v.w);
  *(short4*)(xb + (long)t*HDIM + tid*4) = o;
  __syncthreads();
  #pragma unroll
  for (int j = 0; j < 8; ++j){
    int e = wid*8 + j;
    const float* w = wr + (long)e*HDIM;
    float acc = 0.f;
    for (int k = lane; k < HDIM; k += 64) acc += xs[k]*w[k];
    for (int s = 32; s; s >>= 1) acc += __shfl_xor(acc, s);
    if (lane == 0) lg[e] = acc;
  }
  __syncthreads();
  if (wid == 0){
    float l = (lane < NEXP) ? lg[lane] : -1e30f;
    float m = l;
    for (int s = 32; s; s >>= 1) m = fmaxf(m, __shfl_xor(m, s));
    float p = (lane < NEXP) ? __expf(l - m) : 0.f;
    float sum = p;
    for (int s = 32; s; s >>= 1) sum += __shfl_xor(sum, s);
    p = p / sum;
    float rem = (lane < NEXP) ? (p + bias[lane]) : -1e30f;
    int myidx = 0; float myw = 0.f;
    for (int k = 0; k < TOPK; ++k){
      float vv = rem; int ix = lane;
      for (int s = 32; s; s >>= 1){
        float ov = __shfl_xor(vv, s); int oi = __shfl_xor(ix, s);
        if (ov > vv || (ov == vv && oi < ix)){ vv = ov; ix = oi; }
      }
      float pw = __shfl(p, ix);
      if (lane == ix) rem = -1e30f;
      if (lane == k){ myidx = ix; myw = pw; }
    }
    float s6 = (lane < TOPK) ? myw : 0.f;
    for (int s = 32; s; s >>= 1) s6 += __shfl_xor(s6, s);
    if (lane < TOPK){
      tki[t*TOPK + lane] = myidx;
      tkw[t*TOPK + lane] = myw / fmaxf(s6, 1e-12f);
      atomicAdd(&counts[myidx], 1);
    }
  }
}

__global__ void k_scan(const int* __restrict__ counts, int* __restrict__ offsets,
                       int* __restrict__ cursor){
  if (threadIdx.x == 0){
    int s = 0;
    for (int e = 0; e < NEXP; ++e){ offsets[e] = s; cursor[e] = s; s += counts[e]; }
    offsets[NEXP] = s;
  }
}

__global__ void k_scatter(const int* __restrict__ tki, const float* __restrict__ tkw,
                          int* __restrict__ cursor, int* __restrict__ permt,
                          float* __restrict__ permw){
  int i = blockIdx.x*256 + threadIdx.x;
  if (i < NPAIR){
    int e = tki[i];
    int pos = atomicAdd(&cursor[e], 1);
    permt[pos] = i / TOPK;
    permw[pos] = tkw[i];
  }
}

// ---------------- gate+up, 2-phase pipelined (shared z<2 first) ------------
// z<2: shared half z (n0 = z*512 + x*64), A = xb rows m0.., out -> sb
// z>=2: expert e=z-2 (n0 = x*64), A = gathered xb rows, out -> hmid
__global__ __launch_bounds__(256) void k_gu(const short* __restrict__ xb,
    const float* __restrict__ wgu, const float* __restrict__ wsg,
    const float* __restrict__ wsu, const int* __restrict__ offsets,
    const int* __restrict__ permt, short* __restrict__ hmid, short* __restrict__ sb){
  bool expert = (blockIdx.z >= 2);
  int tid = threadIdx.x, lane = tid & 63, wid = tid >> 6, wr = wid >> 1, wc = wid & 1;
  __shared__ short A0[128*64], A1[128*64], G0[64*64], G1[64*64], U0[64*64], U1[64*64];
  __shared__ int rowmap[128];
  int m0 = blockIdx.y*128, n0;
  int off = 0, seg = NTOK;
  const float *wg, *wu;
  if (expert){
    int e = blockIdx.z - 2;
    off = offsets[e]; seg = offsets[e+1] - off;
    if (m0 >= seg) return;
    n0 = blockIdx.x*64;
    wg = wgu + (long)e*1024*HDIM + (long)n0*HDIM;
    wu = wg + (long)IDIM*HDIM;
    if (tid < 128) rowmap[tid] = permt[off + min(m0 + tid, seg - 1)];
  } else {
    n0 = blockIdx.z*512 + blockIdx.x*64;
    wg = wsg + (long)n0*HDIM;
    wu = wsu + (long)n0*HDIM;
    if (tid < 128) rowmap[tid] = m0 + tid;
  }
  __syncthreads();   // rowmap visible before prologue stage
  auto rowOf = [&](int r){ return rowmap[r]; };
  f32x4 z = {0.f,0.f,0.f,0.f};
  f32x4 ag[4][2], au[4][2];
  for (int i=0;i<4;i++) for (int j=0;j<2;j++){ ag[i][j]=z; au[i][j]=z; }
  float4 bg[2][2], bu[2][2];
  // prologue: stage tile 0 into buf0
  issueA<128>(xb, HDIM, A0, 0, tid, rowOf);
  loadB<64>(wg, HDIM, 0, tid, bg);
  loadB<64>(wu, HDIM, 0, tid, bu);
  writeB<64>(G0, tid, bg);
  writeB<64>(U0, tid, bu);
  __syncthreads();
  short *Ac=A0, *An=A1, *Gc=G0, *Gn=G1, *Uc=U0, *Un=U1;
  for (int kt = 0; kt < HDIM/64; ++kt){
    bool more = (kt+1 < HDIM/64);
    if (more){                                  // issue-early (overlaps MFMA)
      int k1 = (kt+1)*64;
      issueA<128>(xb, HDIM, An, k1, tid, rowOf);
      loadB<64>(wg, HDIM, k1, tid, bg);
      loadB<64>(wu, HDIM, k1, tid, bu);
    }
    #pragma unroll
    for (int ks = 0; ks < 2; ++ks){
      s16x8 af[4], g2[2], u2[2];
      #pragma unroll
      for (int i = 0; i < 4; ++i) af[i] = frag_ld(Ac, wr*64 + i*16 + (lane&15), ks, lane);
      #pragma unroll
      for (int j = 0; j < 2; ++j){
        g2[j] = frag_ld(Gc, wc*32 + j*16 + (lane&15), ks, lane);
        u2[j] = frag_ld(Uc, wc*32 + j*16 + (lane&15), ks, lane);
      }
      #pragma unroll
      for (int i = 0; i < 4; ++i)
        #pragma unroll
        for (int j = 0; j < 2; ++j){
          ag[i][j] = mfma16(af[i], g2[j], ag[i][j]);
          au[i][j] = mfma16(af[i], u2[j], au[i][j]);
        }
    }
    if (more){                                  // write-late (vmcnt by dep)
      writeB<64>(Gn, tid, bg);
      writeB<64>(Un, tid, bu);
    }
    __syncthreads();                            // drains A-dma + B ds_writes
    short* t0=Ac; Ac=An; An=t0;
    short* t1=Gc; Gc=Gn; Gn=t1;
    short* t2=Uc; Uc=Un; Un=t2;
  }
  #pragma unroll
  for (int i = 0; i < 4; ++i){
    int mrow = wr*64 + i*16 + ((lane >> 4) << 2);
    #pragma unroll
    for (int j = 0; j < 2; ++j){
      int col = n0 + wc*32 + j*16 + (lane & 15);
      #pragma unroll
      for (int r = 0; r < 4; ++r){
        int m = mrow + r;
        float gv = ag[i][j][r], uv = au[i][j][r];
        float sv = gv / (1.f + __expf(-gv)) * uv;
        if (expert){
          if (m0 + m < seg)
            hmid[(long)(off + m0 + m)*IDIM + col] = bf1(sv);
        } else {
          sb[(long)(m0 + m)*1024 + col] = bf1(sv);
        }
      }
    }
  }
}

// ---------------- down, 2-phase pipelined (shared z==0 first) --------------
// z==0: shared, A = sb (K=1024), B = wsd, out += acc (atomic; out pre-zeroed)
// z>=1: expert e=z-1, A = hmid segment (K=512), B = wdn[e], out += w*acc
__global__ __launch_bounds__(256) void k_down(const short* __restrict__ hmid,
    const float* __restrict__ wdn, const short* __restrict__ sb,
    const float* __restrict__ wsd, const int* __restrict__ offsets,
    const int* __restrict__ permt, const float* __restrict__ permw,
    float* __restrict__ out){
  bool expert = (blockIdx.z >= 1);
  int tid = threadIdx.x, lane = tid & 63, wid = tid >> 6, wr = wid >> 1, wc = wid & 1;
  __shared__ short A0[128*64], A1[128*64], B0[128*64], B1[128*64];
  __shared__ int rowmap[128];
  int m0 = blockIdx.y*128, n0 = blockIdx.x*128;
  int off = 0, seg = NTOK, nkt, lda, ldb;
  const short* Ag; const float* Bgp;
  if (expert){
    int e = blockIdx.z - 1;
    off = offsets[e]; seg = offsets[e+1] - off;
    if (m0 >= seg) return;
    Ag = hmid; lda = IDIM;
    Bgp = wdn + (long)e*HDIM*IDIM + (long)n0*IDIM; ldb = IDIM;
    nkt = IDIM/64;
    if (tid < 128) rowmap[tid] = off + min(m0 + tid, seg - 1);
  } else {
    Ag = sb; lda = 1024;
    Bgp = wsd + (long)n0*1024; ldb = 1024;
    nkt = 1024/64;
    if (tid < 128) rowmap[tid] = m0 + tid;
  }
  __syncthreads();
  auto rowOf = [&](int r){ return rowmap[r]; };
  f32x4 z = {0.f,0.f,0.f,0.f};
  f32x4 acc[4][4];
  for (int i=0;i<4;i++) for (int j=0;j<4;j++) acc[i][j]=z;
  float4 br[4][2];
  issueA<128>(Ag, lda, A0, 0, tid, rowOf);
  loadB<128>(Bgp, ldb, 0, tid, br);
  writeB<128>(B0, tid, br);
  __syncthreads();
  short *Ac=A0, *An=A1, *Bc=B0, *Bn=B1;
  for (int kt = 0; kt < nkt; ++kt){
    bool more = (kt+1 < nkt);
    if (more){
      int k1 = (kt+1)*64;
      issueA<128>(Ag, lda, An, k1, tid, rowOf);
      loadB<128>(Bgp, ldb, k1, tid, br);
    }
    #pragma unroll
    for (int ks = 0; ks < 2; ++ks){
      s16x8 af[4], bf[4];
      #pragma unroll
      for (int i = 0; i < 4; ++i){
        af[i] = frag_ld(Ac, wr*64 + i*16 + (lane&15), ks, lane);
        bf[i] = frag_ld(Bc, wc*64 + i*16 + (lane&15), ks, lane);
      }
      #pragma unroll
      for (int i = 0; i < 4; ++i)
        #pragma unroll
        for (int j = 0; j < 4; ++j)
          acc[i][j] = mfma16(af[i], bf[j], acc[i][j]);
    }
    if (more) writeB<128>(Bn, tid, br);
    __syncthreads();
    short* t0=Ac; Ac=An; An=t0;
    short* t1=Bc; Bc=Bn; Bn=t1;
  }
  if (expert){
    #pragma unroll
    for (int i = 0; i < 4; ++i){
      int mrow = wr*64 + i*16 + ((lane >> 4) << 2);
      #pragma unroll
      for (int r = 0; r < 4; ++r){
        int m = mrow + r;
        if (m0 + m < seg){
          int p = off + m0 + m;
          int t = permt[p];
          float w = permw[p];
          #pragma unroll
          for (int j = 0; j < 4; ++j){
            int col = n0 + wc*64 + j*16 + (lane & 15);
            atomicAdd(&out[(long)t*HDIM + col], w*acc[i][j][r]);
          }
        }
      }
    }
  } else {
    #pragma unroll
    for (int i = 0; i < 4; ++i){
      int mrow = m0 + wr*64 + i*16 + ((lane >> 4) << 2);
      #pragma unroll
      for (int j = 0; j < 4; ++j){
        int col = n0 + wc*64 + j*16 + (lane & 15);
        #pragma unroll
        for (int r = 0; r < 4; ++r)
          atomicAdd(&out[(long)(mrow + r)*HDIM + col], acc[i][j][r]);
      }
    }
  }
}

extern "C" void kernel_launch(void* const* d_in, const int* in_sizes, int n_in,
                              void* d_out, int out_size, void* d_ws, size_t ws_size,
                              hipStream_t stream){
  const float* x    = (const float*)d_in[0];
  const float* rw   = (const float*)d_in[1];
  const float* bias = (const float*)d_in[2];
  const float* wgu  = (const float*)d_in[3];
  const float* wdn  = (const float*)d_in[4];
  const float* wsg  = (const float*)d_in[5];
  const float* wsu  = (const float*)d_in[6];
  const float* wsd  = (const float*)d_in[7];
  float* out = (float*)d_out;

  char* ws = (char*)d_ws;
  size_t o = 0;
  auto alloc = [&](size_t bytes){ void* p = ws + o; o += (bytes + 255) & ~(size_t)255; return p; };
  short* xb   = (short*)alloc(4194304);    // [T,H] bf16
  short* sb   = (short*)alloc(4194304);    // [T,IS] bf16
  short* hmid = (short*)alloc(12582912);   // [P,I] bf16
  int*   tki  = (int*)alloc(NPAIR*4);
  float* tkw  = (float*)alloc(NPAIR*4);
  int*   counts  = (int*)alloc(256);
  int*   offsets = (int*)alloc(256);
  int*   cursor  = (int*)alloc(256);
  int*   permt   = (int*)alloc(NPAIR*4);
  float* permw   = (float*)alloc(NPAIR*4);
  (void)ws_size; (void)in_sizes; (void)n_in;

  hipMemsetAsync(out, 0, (size_t)out_size*4, stream);
  k_zero<<<dim3(1), dim3(64), 0, stream>>>(counts);
  k_router<<<dim3(NTOK), dim3(256), 0, stream>>>(x, rw, bias, xb, tki, tkw, counts);
  k_scan<<<dim3(1), dim3(64), 0, stream>>>(counts, offsets, cursor);
  k_scatter<<<dim3((NPAIR+255)/256), dim3(256), 0, stream>>>(tki, tkw, cursor, permt, permw);
  k_gu<<<dim3(8, 16, NEXP+2), dim3(256), 0, stream>>>(xb, wgu, wsg, wsu, offsets, permt, hmid, sb);
  k_down<<<dim3(8, 16, NEXP+1), dim3(256), 0, stream>>>(hmid, wdn, sb, wsd, offsets, permt, permw, out);
}